// Round 11
// baseline (383.499 us; speedup 1.0000x reference)
//
#include <hip/hip_runtime.h>
#include <hip/hip_bf16.h>

// HybridSelfAttention: out = softmax((xWq)(xWk)^T / sqrt(d)) (xWv)
// B=4, S=2048, D=1024, fp32 in/out.
//
// Precision: f16 hi/lo split + 3-product MFMA for xWq, xWk, QK^T (softmax is
// near-one-hot; S must be ~fp32-accurate). Plain f16 MFMA for V^T and PV.
//
// R1: LDS chunk swizzle -> bank conflicts 8.4M -> 0.
// R2: dispatch fusion.  R3: MFMA 32x32x16.  R5: swizzle fix -> conflicts 0.
// R6/R7: register-staging transport for GEMM A/B -> spilled -> dead end.
// R8: dbuf LDS, 1 barrier/K-iter -> 888 TF.
// R9-R14: 256^2 8-wave ladder -> 90.5 us (MfmaUtil 50). BEST dbuf K-loop.
// R15: 32x32x16 in R14 schedule regressed (101). R16: softmax->PV fusion
//   regressed (8x fp32 S re-read). R17: pv2 (256x128, per-step vmwait0
//   drain) regressed ~+16 us vs old gemm_nt PV -> reverted.
// R18: pipe accounting of the 50% plateau: per K-step 6790 cyc observed;
//   MFMA pipe 3725 (55%, matches MfmaUtil), LDS pipe ~1500 (25%) -> NEITHER
//   saturated. The gap is latency stalls where the block barrier LOCKSTEPS
//   both waves on a SIMD into the same phase. m97/m114: co-resident
//   INDEPENDENT blocks de-correlate phases. gemm5p's 128KB LDS pins
//   1 block/CU. Experiment (same-run A/B): S-GEMM moves to gemm2b =
//   256x128 tile, BK=32, SINGLE-buffer 48KB LDS, grid 512 = 2 blocks/CU;
//   QK-proj stays on gemm5p as control.
// R19: resubmit of R18 -- infra failed twice with no dispatch/correctness
//   signal (same class as R11/R12, where the identical resubmit passed).
//   Deadlock audit redone: uniform barriers, vmcnt ledger sound, WAR
//   protected by trailing lgkm0+barrier. Kernel byte-identical to R18.

typedef _Float16 half8 __attribute__((ext_vector_type(8)));
typedef _Float16 half4v __attribute__((ext_vector_type(4)));
typedef float f32x16 __attribute__((ext_vector_type(16)));
typedef float f32x4 __attribute__((ext_vector_type(4)));

#define GLOBAL_AS __attribute__((address_space(1)))
#define LDS_AS __attribute__((address_space(3)))

__device__ __forceinline__ void gll16(const _Float16* g, _Float16* l) {
    // async global->LDS DMA, 16B per lane; LDS dest is wave-uniform base + lane*16
    __builtin_amdgcn_global_load_lds((GLOBAL_AS const void*)g, (LDS_AS void*)l, 16, 0, 0);
}

__device__ __forceinline__ void lgkm0_pin() {
    // rule 18: sched_barrier(0) right after an inline-asm lgkmcnt wait.
    asm volatile("s_waitcnt lgkmcnt(0)" ::: "memory");
    __builtin_amdgcn_sched_barrier(0);
}

__device__ __forceinline__ void barrier_fence() {
    asm volatile("s_barrier" ::: "memory");
}

__device__ __forceinline__ void vmwait0() {
    asm volatile("s_waitcnt vmcnt(0)" ::: "memory");
}

__device__ __forceinline__ void vmwait4() {
    asm volatile("s_waitcnt vmcnt(4)" ::: "memory");
}

// ---------------------------------------------------------------------------
// OLD 128x128 kernel (R8 structure) -- V^T (NPROD=1,OUTMODE=2) and PV
// (NPROD=1,OUTMODE=0; ~39 us measured class).
// ---------------------------------------------------------------------------
template <int NPROD, int OUTMODE>
__global__ __launch_bounds__(256) void gemm_nt(
    const _Float16* __restrict__ A0, const _Float16* __restrict__ A1,
    const _Float16* __restrict__ B0, const _Float16* __restrict__ B1,
    float* __restrict__ Cf, _Float16* __restrict__ C0, _Float16* __restrict__ C1,
    int lda, int ldb, int ldc, int K,
    long sA, long sB, long sC, float scale, float scale2) {
    constexpr int NTILES = (NPROD == 3) ? 4 : 2;
    constexpr int BUFH = NTILES * 4096;
    __shared__ alignas(16) _Float16 smem[2 * BUFH];

    const int tid = threadIdx.x;
    const int wave = tid >> 6, lane = tid & 63;
    const int wm = (wave >> 1) * 64, wn = (wave & 1) * 64;
    const int q2 = lane >> 5, r32 = lane & 31;

    const long zA = (long)blockIdx.z * sA;
    const long zB = (long)blockIdx.z * sB;
    const long zC = (long)blockIdx.z * sC;

    const float sc = (blockIdx.y * 2 < gridDim.y) ? scale : scale2;

    const int trow = tid >> 2;
    const int tcol = (((tid & 3) - ((tid >> 3) & 3) - ((tid >> 6) & 3)) & 3) * 8;
    const _Float16* gA0 = A0 + zA + (long)(blockIdx.x * 128 + trow) * lda + tcol;
    const _Float16* gB0 = B0 + zB + (long)(blockIdx.y * 128 + trow) * ldb + tcol;
    const _Float16* gA1 = (NPROD == 3) ? (A1 + zA + (long)(blockIdx.x * 128 + trow) * lda + tcol) : nullptr;
    const _Float16* gB1 = (NPROD == 3) ? (B1 + zB + (long)(blockIdx.y * 128 + trow) * ldb + tcol) : nullptr;

    f32x16 acc[2][2];
#pragma unroll
    for (int i = 0; i < 2; ++i)
#pragma unroll
        for (int j = 0; j < 2; ++j)
#pragma unroll
            for (int r = 0; r < 16; ++r) acc[i][j][r] = 0.f;

    const int ldsoff = tid * 8;
    const int fbase = q2 + (r32 >> 1) + (r32 >> 4);

    {
        _Float16* s = smem;
        gll16(gA0, s + ldsoff);
        gll16(gA0 + 64 * lda, s + ldsoff + 2048);
        gll16(gB0, s + 4096 + ldsoff);
        gll16(gB0 + 64 * ldb, s + 4096 + ldsoff + 2048);
        if (NPROD == 3) {
            gll16(gA1, s + 8192 + ldsoff);
            gll16(gA1 + 64 * lda, s + 8192 + ldsoff + 2048);
            gll16(gB1, s + 12288 + ldsoff);
            gll16(gB1 + 64 * ldb, s + 12288 + ldsoff + 2048);
        }
        gA0 += 32; gB0 += 32;
        if (NPROD == 3) { gA1 += 32; gB1 += 32; }
    }

    int buf = 0;
    for (int k0 = 0; k0 < K; k0 += 32) {
        __syncthreads();

        if (k0 + 32 < K) {
            _Float16* s = smem + (buf ^ 1) * BUFH;
            gll16(gA0, s + ldsoff);
            gll16(gA0 + 64 * lda, s + ldsoff + 2048);
            gll16(gB0, s + 4096 + ldsoff);
            gll16(gB0 + 64 * ldb, s + 4096 + ldsoff + 2048);
            if (NPROD == 3) {
                gll16(gA1, s + 8192 + ldsoff);
                gll16(gA1 + 64 * lda, s + 8192 + ldsoff + 2048);
                gll16(gB1, s + 12288 + ldsoff);
                gll16(gB1 + 64 * ldb, s + 12288 + ldsoff + 2048);
            }
            gA0 += 32; gB0 += 32;
            if (NPROD == 3) { gA1 += 32; gB1 += 32; }
        }

        _Float16* sA0 = smem + buf * BUFH;
        _Float16* sB0 = sA0 + 4096;
        _Float16* sA1 = (NPROD == 3) ? sA0 + 8192 : sA0;
        _Float16* sB1 = (NPROD == 3) ? sA0 + 12288 : sA0;
#pragma unroll
        for (int h = 0; h < 2; ++h) {
            half8 a0[2], b0[2], a1[2], b1[2];
#pragma unroll
            for (int i = 0; i < 2; ++i) {
                const int pp = ((fbase + 2 * i + 2 * h) & 3) * 8;
                a0[i] = *(const half8*)(sA0 + (wm + i * 32 + r32) * 32 + pp);
                b0[i] = *(const half8*)(sB0 + (wn + i * 32 + r32) * 32 + pp);
                if (NPROD == 3) {
                    a1[i] = *(const half8*)(sA1 + (wm + i * 32 + r32) * 32 + pp);
                    b1[i] = *(const half8*)(sB1 + (wn + i * 32 + r32) * 32 + pp);
                }
            }
#pragma unroll
            for (int i = 0; i < 2; ++i)
#pragma unroll
                for (int j = 0; j < 2; ++j) {
                    acc[i][j] = __builtin_amdgcn_mfma_f32_32x32x16_f16(a0[i], b0[j], acc[i][j], 0, 0, 0);
                    if (NPROD == 3) {
                        acc[i][j] = __builtin_amdgcn_mfma_f32_32x32x16_f16(a0[i], b1[j], acc[i][j], 0, 0, 0);
                        acc[i][j] = __builtin_amdgcn_mfma_f32_32x32x16_f16(a1[i], b0[j], acc[i][j], 0, 0, 0);
                    }
                }
        }
        buf ^= 1;
    }

    const int crow0 = blockIdx.x * 128 + wm + 4 * q2;
    const int ccol0 = blockIdx.y * 128 + wn + r32;
#pragma unroll
    for (int i = 0; i < 2; ++i)
#pragma unroll
        for (int j = 0; j < 2; ++j)
#pragma unroll
            for (int r = 0; r < 16; ++r) {
                int row = crow0 + i * 32 + (r & 3) + 8 * (r >> 2);
                long off = zC + (long)row * ldc + (ccol0 + j * 32);
                float v = acc[i][j][r] * sc;
                if (OUTMODE == 0) {
                    Cf[off] = v;
                } else if (OUTMODE == 2) {
                    C0[off] = (_Float16)v;
                } else {
                    _Float16 h = (_Float16)v;
                    C0[off] = h;
                    C1[off] = (_Float16)(v - (float)h);
                }
            }
}

// ---------------------------------------------------------------------------
// R14 gemm5p (dbuf, 256x256, 1 block/CU): kept for QK-proj as the A/B control.
// ---------------------------------------------------------------------------
__device__ __forceinline__ int frag_off(int fb, int lrow, int lc) {
    return (fb + lrow) * 32 + ((((fb >> 4) + lc + (lrow >> 1)) & 3) << 3);
}

__device__ __forceinline__ void ld4(half8 (&d)[4], const _Float16* base, int fb0,
                                    int lrow, int lc) {
#pragma unroll
    for (int f = 0; f < 4; ++f)
        d[f] = *(const half8*)(base + frag_off(fb0 + 16 * f, lrow, lc));
}

template <int MH>
__device__ __forceinline__ void mm16(f32x4 (&acc)[8][4], const half8 (&a)[4],
                                     const half8 (&b)[4]) {
#pragma unroll
    for (int i = 0; i < 4; ++i)
#pragma unroll
        for (int j = 0; j < 4; ++j)
            acc[MH * 4 + i][j] =
                __builtin_amdgcn_mfma_f32_16x16x32_f16(a[i], b[j], acc[MH * 4 + i][j], 0, 0, 0);
}

__device__ __forceinline__ void stage_tile(_Float16* dst, const _Float16* g, int ld,
                                           int ldsoff) {
    gll16(g, dst + ldsoff);
    gll16(g + (long)128 * ld, dst + 4096 + ldsoff);
}

template <int OUTMODE>
__global__ __launch_bounds__(512, 2) void gemm5p(
    const _Float16* __restrict__ A0, const _Float16* __restrict__ A1,
    const _Float16* __restrict__ B0, const _Float16* __restrict__ B1,
    float* __restrict__ Cf, _Float16* __restrict__ C0, _Float16* __restrict__ C1,
    int lda, int ldb, int ldc, int K,
    long sA, long sB, long sC, float scale, float scale2) {
    __shared__ alignas(16) _Float16 smem[65536];  // 128 KiB: 2 x {A0,B0,A1,B1}

    const int tid = threadIdx.x;
    const int wave = tid >> 6, lane = tid & 63;
    const int wm = (wave >> 2) * 128, wn = (wave & 3) * 64;
    const int lrow = lane & 15, lc = lane >> 4;

    const long zA = (long)blockIdx.z * sA;
    const long zB = (long)blockIdx.z * sB;
    const long zC = (long)blockIdx.z * sC;
    const float sc = (blockIdx.y * 2 < gridDim.y) ? scale : scale2;

    const int trow = tid >> 2;
    const int tcol = (((tid & 3) - ((tid >> 3) & 3) - ((tid >> 6) & 3)) & 3) * 8;
    const _Float16* gA0 = A0 + zA + (long)(blockIdx.x * 256 + trow) * lda + tcol;
    const _Float16* gB0 = B0 + zB + (long)(blockIdx.y * 256 + trow) * ldb + tcol;
    const _Float16* gA1 = A1 + zA + (long)(blockIdx.x * 256 + trow) * lda + tcol;
    const _Float16* gB1 = B1 + zB + (long)(blockIdx.y * 256 + trow) * ldb + tcol;

    const int ldsoff = tid * 8;

    f32x4 acc[8][4];
#pragma unroll
    for (int i = 0; i < 8; ++i)
#pragma unroll
        for (int j = 0; j < 4; ++j)
#pragma unroll
            for (int r = 0; r < 4; ++r) acc[i][j][r] = 0.f;

    const int nT = K >> 5;

    {
        _Float16* s = smem;
        stage_tile(s + 0, gA0, lda, ldsoff);
        stage_tile(s + 8192, gB0, ldb, ldsoff);
        stage_tile(s + 16384, gA1, lda, ldsoff);
        stage_tile(s + 24576, gB1, ldb, ldsoff);
        gA0 += 32; gB0 += 32; gA1 += 32; gB1 += 32;
        vmwait4();
        barrier_fence();
    }

    int buf = 0;
    for (int t = 0; t < nT; ++t) {
        _Float16* scur = smem + buf * 32768;
        _Float16* snx = smem + (buf ^ 1) * 32768;
        const bool pre = (t + 1 < nT);

        half8 a0L[4], a0H[4], a1L[4], a1H[4], b0[4], b1[4];

        // ===== region 1: A0-half products; compiler-scheduled =====
        ld4(a0L, scur, wm, lrow, lc);
        ld4(b0, scur + 8192, wn, lrow, lc);
        ld4(a0H, scur, wm + 64, lrow, lc);
        if (pre) {
            stage_tile(snx + 0, gA0, lda, ldsoff); gA0 += 32;
            stage_tile(snx + 8192, gB0, ldb, ldsoff); gB0 += 32;
        }
        __builtin_amdgcn_s_setprio(1);
        mm16<0>(acc, a0L, b0);
        mm16<1>(acc, a0H, b0);
        __builtin_amdgcn_s_setprio(0);
        if (pre) vmwait4();
        else vmwait0();
        barrier_fence();     // publish A1,B1(t)

        // ===== region 2: B1 and A1 products =====
        ld4(b1, scur + 24576, wn, lrow, lc);
        ld4(a1L, scur + 16384, wm, lrow, lc);
        ld4(a1H, scur + 16384, wm + 64, lrow, lc);
        if (pre) {
            stage_tile(snx + 16384, gA1, lda, ldsoff); gA1 += 32;
            stage_tile(snx + 24576, gB1, ldb, ldsoff); gB1 += 32;
        }
        __builtin_amdgcn_s_setprio(1);
        mm16<1>(acc, a0H, b1);
        mm16<0>(acc, a0L, b1);
        mm16<0>(acc, a1L, b0);
        mm16<1>(acc, a1H, b0);
        __builtin_amdgcn_s_setprio(0);
        if (pre) {
            lgkm0_pin();
            vmwait4();
            barrier_fence();  // publish + WAR-protect scur(t)
        }

        buf ^= 1;
    }

    // epilogue: C/D layout col=lane&15, row=(lane>>4)*4+reg
    const int crow0 = blockIdx.x * 256 + wm + lc * 4;
    const int ccol0 = blockIdx.y * 256 + wn + lrow;
#pragma unroll
    for (int mf = 0; mf < 8; ++mf)
#pragma unroll
        for (int nf = 0; nf < 4; ++nf)
#pragma unroll
            for (int r = 0; r < 4; ++r) {
                int row = crow0 + mf * 16 + r;
                long off = zC + (long)row * ldc + (ccol0 + nf * 16);
                float v = acc[mf][nf][r] * sc;
                if (OUTMODE == 0) {
                    Cf[off] = v;
                } else {
                    _Float16 h = (_Float16)v;
                    C0[off] = h;
                    C1[off] = (_Float16)(v - (float)h);
                }
            }
}

// ---------------------------------------------------------------------------
// gemm2b (R18): 256x128 tile, BK=32, SINGLE-buffer 48 KiB LDS -> 2 blocks/CU
// at a 512-block grid. 512 thr = 8 waves (2m x 4n), per-wave 128x32, acc
// 8x2 f32x4. Per K-step: {stage A0,B0,A1,B1 (6 gll16); vmcnt(0); barrier;
// product A0B0 + A0B1 (a-regs, b0, b1 live); reload a-regs from A1; A1B0;
// lgkm0; barrier}. Stage latency exposed within a block -- covered by the
// co-resident sibling block (de-correlated phases; m97/m114 mechanism).
// LDS layout (halves): A0@0 [256][32], B0@8192 [128][32], A1@12288, B1@20480.
// Same frag_off swizzle (conflict-free) and C/D mapping as gemm5p.
// ---------------------------------------------------------------------------
template <int OUTMODE>
__global__ __launch_bounds__(512) void gemm2b(
    const _Float16* __restrict__ A0, const _Float16* __restrict__ A1,
    const _Float16* __restrict__ B0, const _Float16* __restrict__ B1,
    float* __restrict__ Cf, _Float16* __restrict__ C0, _Float16* __restrict__ C1,
    int lda, int ldb, int ldc, int K,
    long sA, long sB, long sC, float scale, float scale2) {
    __shared__ alignas(16) _Float16 smem[24576];  // 48 KiB single buffer

    const int tid = threadIdx.x;
    const int wave = tid >> 6, lane = tid & 63;
    const int wm = (wave >> 2) * 128, wn = (wave & 3) * 32;
    const int lrow = lane & 15, lc = lane >> 4;

    const long zA = (long)blockIdx.z * sA;
    const long zB = (long)blockIdx.z * sB;
    const long zC = (long)blockIdx.z * sC;
    const float sc = (blockIdx.y * 2 < gridDim.y) ? scale : scale2;

    // staging: thread t -> row t>>2 (0..127), phys chunk t&3, logical chunk
    // ((t&3)-f(t>>2))&3; A-tiles use a second gll16 for rows 128..255.
    const int trow = tid >> 2;
    const int tcol = (((tid & 3) - ((tid >> 3) & 3) - ((tid >> 6) & 3)) & 3) * 8;
    const _Float16* gA0 = A0 + zA + (long)(blockIdx.x * 256 + trow) * lda + tcol;
    const _Float16* gB0 = B0 + zB + (long)(blockIdx.y * 128 + trow) * ldb + tcol;
    const _Float16* gA1 = A1 + zA + (long)(blockIdx.x * 256 + trow) * lda + tcol;
    const _Float16* gB1 = B1 + zB + (long)(blockIdx.y * 128 + trow) * ldb + tcol;

    const int ldsoff = tid * 8;

    f32x4 acc[8][2];
#pragma unroll
    for (int i = 0; i < 8; ++i)
#pragma unroll
        for (int j = 0; j < 2; ++j)
#pragma unroll
            for (int r = 0; r < 4; ++r) acc[i][j][r] = 0.f;

    const int nT = K >> 5;

    for (int t = 0; t < nT; ++t) {
        // stage tile t into the single buffer (WAR vs step t-1 protected by
        // the trailing lgkm0+barrier of the previous iteration)
        gll16(gA0, smem + ldsoff);
        gll16(gA0 + 128 * lda, smem + 4096 + ldsoff);
        gll16(gB0, smem + 8192 + ldsoff);
        gll16(gA1, smem + 12288 + ldsoff);
        gll16(gA1 + 128 * lda, smem + 16384 + ldsoff);
        gll16(gB1, smem + 20480 + ldsoff);
        gA0 += 32; gB0 += 32; gA1 += 32; gB1 += 32;
        vmwait0();
        barrier_fence();  // tile visible to all waves

        half8 a[8], b0f[2], b1f[2];
#pragma unroll
        for (int m = 0; m < 8; ++m)
            a[m] = *(const half8*)(smem + frag_off(wm + 16 * m, lrow, lc));
        b0f[0] = *(const half8*)(smem + 8192 + frag_off(wn, lrow, lc));
        b0f[1] = *(const half8*)(smem + 8192 + frag_off(wn + 16, lrow, lc));
        b1f[0] = *(const half8*)(smem + 20480 + frag_off(wn, lrow, lc));
        b1f[1] = *(const half8*)(smem + 20480 + frag_off(wn + 16, lrow, lc));
        __builtin_amdgcn_s_setprio(1);
#pragma unroll
        for (int m = 0; m < 8; ++m)
#pragma unroll
            for (int n = 0; n < 2; ++n)
                acc[m][n] = __builtin_amdgcn_mfma_f32_16x16x32_f16(a[m], b0f[n], acc[m][n], 0, 0, 0);
#pragma unroll
        for (int m = 0; m < 8; ++m)
#pragma unroll
            for (int n = 0; n < 2; ++n)
                acc[m][n] = __builtin_amdgcn_mfma_f32_16x16x32_f16(a[m], b1f[n], acc[m][n], 0, 0, 0);
        __builtin_amdgcn_s_setprio(0);
        // reload a-regs from A1 (caps live VGPR; scheduler hoists these reads
        // into the product-2 MFMA window)
#pragma unroll
        for (int m = 0; m < 8; ++m)
            a[m] = *(const half8*)(smem + 12288 + frag_off(wm + 16 * m, lrow, lc));
        __builtin_amdgcn_s_setprio(1);
#pragma unroll
        for (int m = 0; m < 8; ++m)
#pragma unroll
            for (int n = 0; n < 2; ++n)
                acc[m][n] = __builtin_amdgcn_mfma_f32_16x16x32_f16(a[m], b0f[n], acc[m][n], 0, 0, 0);
        __builtin_amdgcn_s_setprio(0);
        lgkm0_pin();      // this wave's LDS reads complete (WAR for t+1 stage)
        barrier_fence();  // all waves done reading -> buffer reusable
    }

    // epilogue: C/D col=lane&15, row=(lane>>4)*4+reg
    const int crow0 = blockIdx.x * 256 + wm + lc * 4;
    const int ccol0 = blockIdx.y * 128 + wn + lrow;
#pragma unroll
    for (int mf = 0; mf < 8; ++mf)
#pragma unroll
        for (int nf = 0; nf < 2; ++nf)
#pragma unroll
            for (int r = 0; r < 4; ++r) {
                int row = crow0 + mf * 16 + r;
                long off = zC + (long)row * ldc + (ccol0 + nf * 16);
                float v = acc[mf][nf][r] * sc;
                if (OUTMODE == 0) {
                    Cf[off] = v;
                } else {
                    _Float16 h = (_Float16)v;
                    C0[off] = h;
                    C1[off] = (_Float16)(v - (float)h);
                }
            }
}

// ---------------------------------------------------------------------------
// Fused prep: blocks [0, NSPLIT) do the x fp32 -> f16 hi/lo split (x4 vec);
// blocks [NSPLIT, NSPLIT+3072) transpose+split the three weight matrices.
// ---------------------------------------------------------------------------
__global__ __launch_bounds__(256) void prep_fused(
    const float* __restrict__ x, _Float16* __restrict__ x0, _Float16* __restrict__ x1,
    long n4, int nsplit,
    const float* __restrict__ wq, const float* __restrict__ wk,
    const float* __restrict__ wv,
    _Float16* __restrict__ qk0, _Float16* __restrict__ qk1,
    _Float16* __restrict__ v0) {
    __shared__ float t[32][33];
    if ((int)blockIdx.x < nsplit) {
        long i = (long)blockIdx.x * 256 + threadIdx.x;
        if (i >= n4) return;
        float4 v = ((const float4*)x)[i];
        float a[4] = {v.x, v.y, v.z, v.w};
        half4v h, l;
#pragma unroll
        for (int c = 0; c < 4; ++c) {
            h[c] = (_Float16)a[c];
            l[c] = (_Float16)(a[c] - (float)h[c]);
        }
        ((half4v*)x0)[i] = h;
        ((half4v*)x1)[i] = l;
        return;
    }
    const int idx = blockIdx.x - nsplit;
    const int z = idx >> 10;
    const int tile = idx & 1023;
    const float* in = (z == 0) ? wq : (z == 1) ? wk : wv;
    _Float16* o0 = (z == 0) ? qk0 : (z == 1) ? qk0 + 1024 * 1024 : v0;
    _Float16* o1 = (z == 0) ? qk1 : qk1 + 1024 * 1024;  // z==2 has no lo part

    const int c0 = (tile & 31) * 32, r0 = (tile >> 5) * 32;
    const int tx = threadIdx.x & 31, ty = threadIdx.x >> 5;
#pragma unroll
    for (int i = 0; i < 32; i += 8)
        t[ty + i][tx] = in[(long)(r0 + ty + i) * 1024 + c0 + tx];
    __syncthreads();
#pragma unroll
    for (int i = 0; i < 32; i += 8) {
        float v = t[tx][ty + i];
        _Float16 h = (_Float16)v;
        long o = (long)(c0 + ty + i) * 1024 + r0 + tx;
        o0[o] = h;
        if (z < 2) o1[o] = (_Float16)(v - (float)h);
    }
}

// ---------------------------------------------------------------------------
// row softmax: S fp32 [8192][2048] -> P f16, one block per row (vectorized)
// ---------------------------------------------------------------------------
__global__ __launch_bounds__(256) void softmax_rows(const float* __restrict__ S,
                                                    _Float16* __restrict__ P) {
    const int n = 2048;
    const long base = (long)blockIdx.x * n;
    const float4* row4 = (const float4*)(S + base);
    const int tid = threadIdx.x;
    const int wave = tid >> 6;

    float4 v0 = row4[tid * 2];
    float4 v1 = row4[tid * 2 + 1];
    float v[8] = {v0.x, v0.y, v0.z, v0.w, v1.x, v1.y, v1.z, v1.w};
    float lm = -3.4e38f;
#pragma unroll
    for (int t = 0; t < 8; ++t) lm = fmaxf(lm, v[t]);
#pragma unroll
    for (int o = 32; o > 0; o >>= 1) lm = fmaxf(lm, __shfl_xor(lm, o));
    __shared__ float redm[4];
    __shared__ float reds[4];
    if ((tid & 63) == 0) redm[wave] = lm;
    __syncthreads();
    lm = fmaxf(fmaxf(redm[0], redm[1]), fmaxf(redm[2], redm[3]));

    float e[8];
    float ls = 0.f;
#pragma unroll
    for (int t = 0; t < 8; ++t) {
        e[t] = __expf(v[t] - lm);
        ls += e[t];
    }
#pragma unroll
    for (int o = 32; o > 0; o >>= 1) ls += __shfl_xor(ls, o);
    if ((tid & 63) == 0) reds[wave] = ls;
    __syncthreads();
    ls = reds[0] + reds[1] + reds[2] + reds[3];
    const float inv = 1.f / ls;
    half8 p;
#pragma unroll
    for (int t = 0; t < 8; ++t) p[t] = (_Float16)(e[t] * inv);
    ((half8*)(P + base))[tid] = p;
}

// ---------------------------------------------------------------------------
extern "C" void kernel_launch(void* const* d_in, const int* in_sizes, int n_in,
                              void* d_out, int out_size, void* d_ws, size_t ws_size,
                              hipStream_t stream) {
    (void)in_sizes; (void)n_in; (void)out_size; (void)ws_size;
    const float* x = (const float*)d_in[0];
    const float* wq = (const float*)d_in[1];
    const float* wk = (const float*)d_in[2];
    const float* wv = (const float*)d_in[3];
    float* out = (float*)d_out;
    char* ws = (char*)d_ws;

    const long MB = 1l << 20;
    // ws layout (188 MB):
    _Float16* Wqk0 = (_Float16*)(ws + 0 * MB);   // [2048][1024] 4 MB
    _Float16* Wqk1 = (_Float16*)(ws + 4 * MB);   // 4 MB
    _Float16* Wv0  = (_Float16*)(ws + 8 * MB);   // 2 MB (Wv^T, hi only)
    _Float16* x0   = (_Float16*)(ws + 12 * MB);  // 16 MB
    _Float16* x1   = (_Float16*)(ws + 28 * MB);  // 16 MB
    _Float16* P    = (_Float16*)(ws + 12 * MB);  // 32 MB, reuses dead x0/x1
    _Float16* QK0  = (_Float16*)(ws + 44 * MB);  // [8192][2048] 32 MB
    _Float16* QK1  = (_Float16*)(ws + 76 * MB);  // 32 MB
    _Float16* Vt   = (_Float16*)(ws + 108 * MB); // [1024][8192] 16 MB
    float*    S    = (float*)(ws + 124 * MB);    // 64 MB

    const int B = 4, SEQ = 2048, D = 1024;
    const long M = (long)B * SEQ;  // 8192
    const long ssq = (long)SEQ * SEQ;  // per-batch S stride
    const int nsplit = (int)((M * D / 4 + 255) / 256);  // 8192

    // 1) fused prep: x split + weight transpose/split
    prep_fused<<<dim3(nsplit + 3072), dim3(256), 0, stream>>>(
        x, x0, x1, M * D / 4, nsplit, wq, wk, wv, Wqk0, Wqk1, Wv0);

    // 2) fused Q|K projection (R14 gemm5p, CONTROL): QK[m][n], hi/lo split
    gemm5p<1><<<dim3(32, 8, 1), dim3(512), 0, stream>>>(
        x0, x1, Wqk0, Wqk1, nullptr, QK0, QK1, D, D, 2 * D, D,
        0, 0, 0, 0.03125f, 1.0f);

    // 3) V^T: Vt[e][m] = sum_d Wv^T[e][d] * x[m][d]  (NT, A=Wv^T, B=x)
    gemm_nt<1, 2><<<dim3(8, 64, 1), dim3(256), 0, stream>>>(
        Wv0, nullptr, x0, nullptr, nullptr, Vt, nullptr, D, D, (int)M, D,
        0, 0, 0, 1.0f, 1.0f);

    // 4) S = Qs @ K^T via gemm2b (EXPERIMENT: 256x128, 2 blocks/CU)
    gemm2b<0><<<dim3(8, 16, B), dim3(512), 0, stream>>>(
        QK0, QK1, QK0 + D, QK1 + D, S, nullptr, nullptr, 2 * D, 2 * D, SEQ, D,
        (long)SEQ * 2 * D, (long)SEQ * 2 * D, ssq, 1.0f, 1.0f);

    // 5) P = rowsoftmax(S) as f16
    softmax_rows<<<dim3(B * SEQ), dim3(256), 0, stream>>>(S, P);

    // 6) out = P @ V via gemm_nt (REVERTED from pv2; ~39 us class)
    gemm_nt<1, 0><<<dim3(16, 8, B), dim3(256), 0, stream>>>(
        P, nullptr, Vt, nullptr, out, nullptr, nullptr, SEQ, (int)M, D, SEQ,
        ssq, (long)SEQ, (long)SEQ * D, 1.0f, 1.0f);
}

// Round 12
// 358.081 us; speedup vs baseline: 1.0710x; 1.0710x over previous
//
#include <hip/hip_runtime.h>
#include <hip/hip_bf16.h>

// HybridSelfAttention: out = softmax((xWq)(xWk)^T / sqrt(d)) (xWv)
// B=4, S=2048, D=1024, fp32 in/out.
//
// Precision: f16 hi/lo split + 3-product MFMA for xWq, xWk, QK^T (softmax is
// near-one-hot; S must be ~fp32-accurate). Plain f16 MFMA for V^T and PV.
//
// R1: LDS chunk swizzle -> bank conflicts 8.4M -> 0.
// R2: dispatch fusion.  R3: MFMA 32x32x16.  R5: swizzle fix -> conflicts 0.
// R6/R7: register-staging transport for GEMM A/B -> spilled -> dead end.
// R8: dbuf LDS, 1 barrier/K-iter -> 888 TF.
// R9-R14: 256^2 8-wave ladder -> 90.5 us (MfmaUtil 50). BEST K-loop.
// R15: 32x32x16 in R14 schedule regressed (101): interleave granularity, not
//   pipe peak, limits at ~50% util.
// R16: softmax->PV fusion regressed (8x fp32 S re-read beats 8x f16 P re-read
//   + separate BW-bound softmax only on paper).
// R17: pv2 (per-step vmwait0 drain) regressed vs gemm_nt PV.
// R18/R19: co-residency experiment FALSIFIED: gemm2b (256x128, single-buffer
//   48KB, 2 blocks/CU) = 136.5 us, MfmaUtil 31, Occupancy 21. Both resident
//   blocks sit in the same exposed vmwait0 HBM drain each step -- siblings
//   are latency-bound simultaneously, not phase-shifted partners. The dbuf
//   pipeline (hides staging entirely) beats 2-block scheduling effects.
// R20: consolidate measured-best config: gemm5p (R14) for QK-proj AND S,
//   gemm_nt for V^T and PV, lean prep (no Wv1), softmax_rows. Every dispatch
//   here is its measured-best variant. Next candidate (not bundled): 1-product
//   gemm5p for V^T.

typedef _Float16 half8 __attribute__((ext_vector_type(8)));
typedef _Float16 half4v __attribute__((ext_vector_type(4)));
typedef float f32x16 __attribute__((ext_vector_type(16)));
typedef float f32x4 __attribute__((ext_vector_type(4)));

#define GLOBAL_AS __attribute__((address_space(1)))
#define LDS_AS __attribute__((address_space(3)))

__device__ __forceinline__ void gll16(const _Float16* g, _Float16* l) {
    // async global->LDS DMA, 16B per lane; LDS dest is wave-uniform base + lane*16
    __builtin_amdgcn_global_load_lds((GLOBAL_AS const void*)g, (LDS_AS void*)l, 16, 0, 0);
}

__device__ __forceinline__ void lgkm0_pin() {
    // rule 18: sched_barrier(0) right after an inline-asm lgkmcnt wait.
    asm volatile("s_waitcnt lgkmcnt(0)" ::: "memory");
    __builtin_amdgcn_sched_barrier(0);
}

__device__ __forceinline__ void barrier_fence() {
    asm volatile("s_barrier" ::: "memory");
}

__device__ __forceinline__ void vmwait0() {
    asm volatile("s_waitcnt vmcnt(0)" ::: "memory");
}

__device__ __forceinline__ void vmwait4() {
    asm volatile("s_waitcnt vmcnt(4)" ::: "memory");
}

// ---------------------------------------------------------------------------
// 128x128 kernel (R8 structure) -- V^T (NPROD=1,OUTMODE=2) and PV
// (NPROD=1,OUTMODE=0). dbuf LDS, one barrier per K-iter; ~880 TF class for
// NPROD=3, and the best measured PV (~39 us class).
// ---------------------------------------------------------------------------
template <int NPROD, int OUTMODE>
__global__ __launch_bounds__(256) void gemm_nt(
    const _Float16* __restrict__ A0, const _Float16* __restrict__ A1,
    const _Float16* __restrict__ B0, const _Float16* __restrict__ B1,
    float* __restrict__ Cf, _Float16* __restrict__ C0, _Float16* __restrict__ C1,
    int lda, int ldb, int ldc, int K,
    long sA, long sB, long sC, float scale, float scale2) {
    constexpr int NTILES = (NPROD == 3) ? 4 : 2;
    constexpr int BUFH = NTILES * 4096;
    __shared__ alignas(16) _Float16 smem[2 * BUFH];

    const int tid = threadIdx.x;
    const int wave = tid >> 6, lane = tid & 63;
    const int wm = (wave >> 1) * 64, wn = (wave & 1) * 64;
    const int q2 = lane >> 5, r32 = lane & 31;

    const long zA = (long)blockIdx.z * sA;
    const long zB = (long)blockIdx.z * sB;
    const long zC = (long)blockIdx.z * sC;

    const float sc = (blockIdx.y * 2 < gridDim.y) ? scale : scale2;

    const int trow = tid >> 2;
    const int tcol = (((tid & 3) - ((tid >> 3) & 3) - ((tid >> 6) & 3)) & 3) * 8;
    const _Float16* gA0 = A0 + zA + (long)(blockIdx.x * 128 + trow) * lda + tcol;
    const _Float16* gB0 = B0 + zB + (long)(blockIdx.y * 128 + trow) * ldb + tcol;
    const _Float16* gA1 = (NPROD == 3) ? (A1 + zA + (long)(blockIdx.x * 128 + trow) * lda + tcol) : nullptr;
    const _Float16* gB1 = (NPROD == 3) ? (B1 + zB + (long)(blockIdx.y * 128 + trow) * ldb + tcol) : nullptr;

    f32x16 acc[2][2];
#pragma unroll
    for (int i = 0; i < 2; ++i)
#pragma unroll
        for (int j = 0; j < 2; ++j)
#pragma unroll
            for (int r = 0; r < 16; ++r) acc[i][j][r] = 0.f;

    const int ldsoff = tid * 8;
    const int fbase = q2 + (r32 >> 1) + (r32 >> 4);

    {
        _Float16* s = smem;
        gll16(gA0, s + ldsoff);
        gll16(gA0 + 64 * lda, s + ldsoff + 2048);
        gll16(gB0, s + 4096 + ldsoff);
        gll16(gB0 + 64 * ldb, s + 4096 + ldsoff + 2048);
        if (NPROD == 3) {
            gll16(gA1, s + 8192 + ldsoff);
            gll16(gA1 + 64 * lda, s + 8192 + ldsoff + 2048);
            gll16(gB1, s + 12288 + ldsoff);
            gll16(gB1 + 64 * ldb, s + 12288 + ldsoff + 2048);
        }
        gA0 += 32; gB0 += 32;
        if (NPROD == 3) { gA1 += 32; gB1 += 32; }
    }

    int buf = 0;
    for (int k0 = 0; k0 < K; k0 += 32) {
        __syncthreads();

        if (k0 + 32 < K) {
            _Float16* s = smem + (buf ^ 1) * BUFH;
            gll16(gA0, s + ldsoff);
            gll16(gA0 + 64 * lda, s + ldsoff + 2048);
            gll16(gB0, s + 4096 + ldsoff);
            gll16(gB0 + 64 * ldb, s + 4096 + ldsoff + 2048);
            if (NPROD == 3) {
                gll16(gA1, s + 8192 + ldsoff);
                gll16(gA1 + 64 * lda, s + 8192 + ldsoff + 2048);
                gll16(gB1, s + 12288 + ldsoff);
                gll16(gB1 + 64 * ldb, s + 12288 + ldsoff + 2048);
            }
            gA0 += 32; gB0 += 32;
            if (NPROD == 3) { gA1 += 32; gB1 += 32; }
        }

        _Float16* sA0 = smem + buf * BUFH;
        _Float16* sB0 = sA0 + 4096;
        _Float16* sA1 = (NPROD == 3) ? sA0 + 8192 : sA0;
        _Float16* sB1 = (NPROD == 3) ? sA0 + 12288 : sA0;
#pragma unroll
        for (int h = 0; h < 2; ++h) {
            half8 a0[2], b0[2], a1[2], b1[2];
#pragma unroll
            for (int i = 0; i < 2; ++i) {
                const int pp = ((fbase + 2 * i + 2 * h) & 3) * 8;
                a0[i] = *(const half8*)(sA0 + (wm + i * 32 + r32) * 32 + pp);
                b0[i] = *(const half8*)(sB0 + (wn + i * 32 + r32) * 32 + pp);
                if (NPROD == 3) {
                    a1[i] = *(const half8*)(sA1 + (wm + i * 32 + r32) * 32 + pp);
                    b1[i] = *(const half8*)(sB1 + (wn + i * 32 + r32) * 32 + pp);
                }
            }
#pragma unroll
            for (int i = 0; i < 2; ++i)
#pragma unroll
                for (int j = 0; j < 2; ++j) {
                    acc[i][j] = __builtin_amdgcn_mfma_f32_32x32x16_f16(a0[i], b0[j], acc[i][j], 0, 0, 0);
                    if (NPROD == 3) {
                        acc[i][j] = __builtin_amdgcn_mfma_f32_32x32x16_f16(a0[i], b1[j], acc[i][j], 0, 0, 0);
                        acc[i][j] = __builtin_amdgcn_mfma_f32_32x32x16_f16(a1[i], b0[j], acc[i][j], 0, 0, 0);
                    }
                }
        }
        buf ^= 1;
    }

    const int crow0 = blockIdx.x * 128 + wm + 4 * q2;
    const int ccol0 = blockIdx.y * 128 + wn + r32;
#pragma unroll
    for (int i = 0; i < 2; ++i)
#pragma unroll
        for (int j = 0; j < 2; ++j)
#pragma unroll
            for (int r = 0; r < 16; ++r) {
                int row = crow0 + i * 32 + (r & 3) + 8 * (r >> 2);
                long off = zC + (long)row * ldc + (ccol0 + j * 32);
                float v = acc[i][j][r] * sc;
                if (OUTMODE == 0) {
                    Cf[off] = v;
                } else if (OUTMODE == 2) {
                    C0[off] = (_Float16)v;
                } else {
                    _Float16 h = (_Float16)v;
                    C0[off] = h;
                    C1[off] = (_Float16)(v - (float)h);
                }
            }
}

// ---------------------------------------------------------------------------
// R14 gemm5p (BEST, measured 90.5 us / MfmaUtil 50): 256x256-tile, 8-wave,
// 2 barriers/K-step, compiler-scheduled LDS reads, MFMA 16x16x32.
// C = (A0+A1)(B0+B1)^T ~= A0B0 + A0B1 + A1B0.
// 512 thr = 8 waves (2M x 4N), per-wave 128x64 output, acc = 32 x f32x4.
// Swizzle: phys chunk = (c + f(r))&3, f(r)=((r>>1)+(r>>4))&3; for a 16-row
// fragment at base FB: f == (FB>>4 + ((lane&15)>>1)) & 3 -> conflict-free.
// vmcnt ledger (per-wave, in-order): prologue 8 -> vmwait4 leaves A1,B1(0).
// Steady: r1 +4 -> 8; vmwait4 forces oldest 4 = A1,B1(t). r2 +4 -> 8;
// vmwait4 forces oldest 4 = A0,B0(t+1). Last iter: r1 vmwait0 drains.
// ---------------------------------------------------------------------------
__device__ __forceinline__ int frag_off(int fb, int lrow, int lc) {
    return (fb + lrow) * 32 + ((((fb >> 4) + lc + (lrow >> 1)) & 3) << 3);
}

__device__ __forceinline__ void ld4(half8 (&d)[4], const _Float16* base, int fb0,
                                    int lrow, int lc) {
#pragma unroll
    for (int f = 0; f < 4; ++f)
        d[f] = *(const half8*)(base + frag_off(fb0 + 16 * f, lrow, lc));
}

template <int MH>
__device__ __forceinline__ void mm16(f32x4 (&acc)[8][4], const half8 (&a)[4],
                                     const half8 (&b)[4]) {
#pragma unroll
    for (int i = 0; i < 4; ++i)
#pragma unroll
        for (int j = 0; j < 4; ++j)
            acc[MH * 4 + i][j] =
                __builtin_amdgcn_mfma_f32_16x16x32_f16(a[i], b[j], acc[MH * 4 + i][j], 0, 0, 0);
}

__device__ __forceinline__ void stage_tile(_Float16* dst, const _Float16* g, int ld,
                                           int ldsoff) {
    gll16(g, dst + ldsoff);
    gll16(g + (long)128 * ld, dst + 4096 + ldsoff);
}

template <int OUTMODE>
__global__ __launch_bounds__(512, 2) void gemm5p(
    const _Float16* __restrict__ A0, const _Float16* __restrict__ A1,
    const _Float16* __restrict__ B0, const _Float16* __restrict__ B1,
    float* __restrict__ Cf, _Float16* __restrict__ C0, _Float16* __restrict__ C1,
    int lda, int ldb, int ldc, int K,
    long sA, long sB, long sC, float scale, float scale2) {
    __shared__ alignas(16) _Float16 smem[65536];  // 128 KiB: 2 x {A0,B0,A1,B1}

    const int tid = threadIdx.x;
    const int wave = tid >> 6, lane = tid & 63;
    const int wm = (wave >> 2) * 128, wn = (wave & 3) * 64;
    const int lrow = lane & 15, lc = lane >> 4;

    const long zA = (long)blockIdx.z * sA;
    const long zB = (long)blockIdx.z * sB;
    const long zC = (long)blockIdx.z * sC;
    const float sc = (blockIdx.y * 2 < gridDim.y) ? scale : scale2;

    const int trow = tid >> 2;
    const int tcol = (((tid & 3) - ((tid >> 3) & 3) - ((tid >> 6) & 3)) & 3) * 8;
    const _Float16* gA0 = A0 + zA + (long)(blockIdx.x * 256 + trow) * lda + tcol;
    const _Float16* gB0 = B0 + zB + (long)(blockIdx.y * 256 + trow) * ldb + tcol;
    const _Float16* gA1 = A1 + zA + (long)(blockIdx.x * 256 + trow) * lda + tcol;
    const _Float16* gB1 = B1 + zB + (long)(blockIdx.y * 256 + trow) * ldb + tcol;

    const int ldsoff = tid * 8;

    f32x4 acc[8][4];
#pragma unroll
    for (int i = 0; i < 8; ++i)
#pragma unroll
        for (int j = 0; j < 4; ++j)
#pragma unroll
            for (int r = 0; r < 4; ++r) acc[i][j][r] = 0.f;

    const int nT = K >> 5;

    {
        _Float16* s = smem;
        stage_tile(s + 0, gA0, lda, ldsoff);
        stage_tile(s + 8192, gB0, ldb, ldsoff);
        stage_tile(s + 16384, gA1, lda, ldsoff);
        stage_tile(s + 24576, gB1, ldb, ldsoff);
        gA0 += 32; gB0 += 32; gA1 += 32; gB1 += 32;
        vmwait4();
        barrier_fence();
    }

    int buf = 0;
    for (int t = 0; t < nT; ++t) {
        _Float16* scur = smem + buf * 32768;
        _Float16* snx = smem + (buf ^ 1) * 32768;
        const bool pre = (t + 1 < nT);

        half8 a0L[4], a0H[4], a1L[4], a1H[4], b0[4], b1[4];

        // ===== region 1: A0-half products; compiler-scheduled =====
        ld4(a0L, scur, wm, lrow, lc);
        ld4(b0, scur + 8192, wn, lrow, lc);
        ld4(a0H, scur, wm + 64, lrow, lc);
        if (pre) {
            stage_tile(snx + 0, gA0, lda, ldsoff); gA0 += 32;
            stage_tile(snx + 8192, gB0, ldb, ldsoff); gB0 += 32;
        }
        __builtin_amdgcn_s_setprio(1);
        mm16<0>(acc, a0L, b0);
        mm16<1>(acc, a0H, b0);
        __builtin_amdgcn_s_setprio(0);
        if (pre) vmwait4();
        else vmwait0();
        barrier_fence();     // publish A1,B1(t)

        // ===== region 2: B1 and A1 products =====
        ld4(b1, scur + 24576, wn, lrow, lc);
        ld4(a1L, scur + 16384, wm, lrow, lc);
        ld4(a1H, scur + 16384, wm + 64, lrow, lc);
        if (pre) {
            stage_tile(snx + 16384, gA1, lda, ldsoff); gA1 += 32;
            stage_tile(snx + 24576, gB1, ldb, ldsoff); gB1 += 32;
        }
        __builtin_amdgcn_s_setprio(1);
        mm16<1>(acc, a0H, b1);
        mm16<0>(acc, a0L, b1);
        mm16<0>(acc, a1L, b0);
        mm16<1>(acc, a1H, b0);
        __builtin_amdgcn_s_setprio(0);
        if (pre) {
            lgkm0_pin();
            vmwait4();
            barrier_fence();  // publish + WAR-protect scur(t)
        }

        buf ^= 1;
    }

    // epilogue: C/D layout col=lane&15, row=(lane>>4)*4+reg
    const int crow0 = blockIdx.x * 256 + wm + lc * 4;
    const int ccol0 = blockIdx.y * 256 + wn + lrow;
#pragma unroll
    for (int mf = 0; mf < 8; ++mf)
#pragma unroll
        for (int nf = 0; nf < 4; ++nf)
#pragma unroll
            for (int r = 0; r < 4; ++r) {
                int row = crow0 + mf * 16 + r;
                long off = zC + (long)row * ldc + (ccol0 + nf * 16);
                float v = acc[mf][nf][r] * sc;
                if (OUTMODE == 0) {
                    Cf[off] = v;
                } else {
                    _Float16 h = (_Float16)v;
                    C0[off] = h;
                    C1[off] = (_Float16)(v - (float)h);
                }
            }
}

// ---------------------------------------------------------------------------
// Fused prep: blocks [0, NSPLIT) do the x fp32 -> f16 hi/lo split (x4 vec);
// blocks [NSPLIT, NSPLIT+3072) transpose+split the three weight matrices.
// ---------------------------------------------------------------------------
__global__ __launch_bounds__(256) void prep_fused(
    const float* __restrict__ x, _Float16* __restrict__ x0, _Float16* __restrict__ x1,
    long n4, int nsplit,
    const float* __restrict__ wq, const float* __restrict__ wk,
    const float* __restrict__ wv,
    _Float16* __restrict__ qk0, _Float16* __restrict__ qk1,
    _Float16* __restrict__ v0) {
    __shared__ float t[32][33];
    if ((int)blockIdx.x < nsplit) {
        long i = (long)blockIdx.x * 256 + threadIdx.x;
        if (i >= n4) return;
        float4 v = ((const float4*)x)[i];
        float a[4] = {v.x, v.y, v.z, v.w};
        half4v h, l;
#pragma unroll
        for (int c = 0; c < 4; ++c) {
            h[c] = (_Float16)a[c];
            l[c] = (_Float16)(a[c] - (float)h[c]);
        }
        ((half4v*)x0)[i] = h;
        ((half4v*)x1)[i] = l;
        return;
    }
    const int idx = blockIdx.x - nsplit;
    const int z = idx >> 10;
    const int tile = idx & 1023;
    const float* in = (z == 0) ? wq : (z == 1) ? wk : wv;
    _Float16* o0 = (z == 0) ? qk0 : (z == 1) ? qk0 + 1024 * 1024 : v0;
    _Float16* o1 = (z == 0) ? qk1 : qk1 + 1024 * 1024;  // z==2 has no lo part

    const int c0 = (tile & 31) * 32, r0 = (tile >> 5) * 32;
    const int tx = threadIdx.x & 31, ty = threadIdx.x >> 5;
#pragma unroll
    for (int i = 0; i < 32; i += 8)
        t[ty + i][tx] = in[(long)(r0 + ty + i) * 1024 + c0 + tx];
    __syncthreads();
#pragma unroll
    for (int i = 0; i < 32; i += 8) {
        float v = t[tx][ty + i];
        _Float16 h = (_Float16)v;
        long o = (long)(c0 + ty + i) * 1024 + r0 + tx;
        o0[o] = h;
        if (z < 2) o1[o] = (_Float16)(v - (float)h);
    }
}

// ---------------------------------------------------------------------------
// row softmax: S fp32 [8192][2048] -> P f16, one block per row (vectorized)
// ---------------------------------------------------------------------------
__global__ __launch_bounds__(256) void softmax_rows(const float* __restrict__ S,
                                                    _Float16* __restrict__ P) {
    const int n = 2048;
    const long base = (long)blockIdx.x * n;
    const float4* row4 = (const float4*)(S + base);
    const int tid = threadIdx.x;
    const int wave = tid >> 6;

    float4 v0 = row4[tid * 2];
    float4 v1 = row4[tid * 2 + 1];
    float v[8] = {v0.x, v0.y, v0.z, v0.w, v1.x, v1.y, v1.z, v1.w};
    float lm = -3.4e38f;
#pragma unroll
    for (int t = 0; t < 8; ++t) lm = fmaxf(lm, v[t]);
#pragma unroll
    for (int o = 32; o > 0; o >>= 1) lm = fmaxf(lm, __shfl_xor(lm, o));
    __shared__ float redm[4];
    __shared__ float reds[4];
    if ((tid & 63) == 0) redm[wave] = lm;
    __syncthreads();
    lm = fmaxf(fmaxf(redm[0], redm[1]), fmaxf(redm[2], redm[3]));

    float e[8];
    float ls = 0.f;
#pragma unroll
    for (int t = 0; t < 8; ++t) {
        e[t] = __expf(v[t] - lm);
        ls += e[t];
    }
#pragma unroll
    for (int o = 32; o > 0; o >>= 1) ls += __shfl_xor(ls, o);
    if ((tid & 63) == 0) reds[wave] = ls;
    __syncthreads();
    ls = reds[0] + reds[1] + reds[2] + reds[3];
    const float inv = 1.f / ls;
    half8 p;
#pragma unroll
    for (int t = 0; t < 8; ++t) p[t] = (_Float16)(e[t] * inv);
    ((half8*)(P + base))[tid] = p;
}

// ---------------------------------------------------------------------------
extern "C" void kernel_launch(void* const* d_in, const int* in_sizes, int n_in,
                              void* d_out, int out_size, void* d_ws, size_t ws_size,
                              hipStream_t stream) {
    (void)in_sizes; (void)n_in; (void)out_size; (void)ws_size;
    const float* x = (const float*)d_in[0];
    const float* wq = (const float*)d_in[1];
    const float* wk = (const float*)d_in[2];
    const float* wv = (const float*)d_in[3];
    float* out = (float*)d_out;
    char* ws = (char*)d_ws;

    const long MB = 1l << 20;
    // ws layout (188 MB):
    _Float16* Wqk0 = (_Float16*)(ws + 0 * MB);   // [2048][1024] 4 MB
    _Float16* Wqk1 = (_Float16*)(ws + 4 * MB);   // 4 MB
    _Float16* Wv0  = (_Float16*)(ws + 8 * MB);   // 2 MB (Wv^T, hi only)
    _Float16* x0   = (_Float16*)(ws + 12 * MB);  // 16 MB
    _Float16* x1   = (_Float16*)(ws + 28 * MB);  // 16 MB
    _Float16* P    = (_Float16*)(ws + 12 * MB);  // 32 MB, reuses dead x0/x1
    _Float16* QK0  = (_Float16*)(ws + 44 * MB);  // [8192][2048] 32 MB
    _Float16* QK1  = (_Float16*)(ws + 76 * MB);  // 32 MB
    _Float16* Vt   = (_Float16*)(ws + 108 * MB); // [1024][8192] 16 MB
    float*    S    = (float*)(ws + 124 * MB);    // 64 MB

    const int B = 4, SEQ = 2048, D = 1024;
    const long M = (long)B * SEQ;  // 8192
    const long ssq = (long)SEQ * SEQ;  // per-batch S stride
    const int nsplit = (int)((M * D / 4 + 255) / 256);  // 8192

    // 1) fused prep: x split + weight transpose/split
    prep_fused<<<dim3(nsplit + 3072), dim3(256), 0, stream>>>(
        x, x0, x1, M * D / 4, nsplit, wq, wk, wv, Wqk0, Wqk1, Wv0);

    // 2) fused Q|K projection (R14 gemm5p): QK[m][n], hi/lo split out
    gemm5p<1><<<dim3(32, 8, 1), dim3(512), 0, stream>>>(
        x0, x1, Wqk0, Wqk1, nullptr, QK0, QK1, D, D, 2 * D, D,
        0, 0, 0, 0.03125f, 1.0f);

    // 3) V^T: Vt[e][m] = sum_d Wv^T[e][d] * x[m][d]  (NT, A=Wv^T, B=x)
    gemm_nt<1, 2><<<dim3(8, 64, 1), dim3(256), 0, stream>>>(
        Wv0, nullptr, x0, nullptr, nullptr, Vt, nullptr, D, D, (int)M, D,
        0, 0, 0, 1.0f, 1.0f);

    // 4) S = Qs @ K^T (R14 gemm5p, fp32 out)
    gemm5p<0><<<dim3(8, 8, B), dim3(512), 0, stream>>>(
        QK0, QK1, QK0 + D, QK1 + D, S, nullptr, nullptr, 2 * D, 2 * D, SEQ, D,
        (long)SEQ * 2 * D, (long)SEQ * 2 * D, ssq, 1.0f, 1.0f);

    // 5) P = rowsoftmax(S) as f16
    softmax_rows<<<dim3(B * SEQ), dim3(256), 0, stream>>>(S, P);

    // 6) out = P @ V via gemm_nt (best measured PV)
    gemm_nt<1, 0><<<dim3(16, 8, B), dim3(256), 0, stream>>>(
        P, nullptr, Vt, nullptr, out, nullptr, nullptr, SEQ, (int)M, D, SEQ,
        ssq, (long)SEQ, (long)SEQ * D, 1.0f, 1.0f);
}